// Round 1
// baseline (34.412 us; speedup 1.0000x reference)
//
#include <hip/hip_runtime.h>

// Problem constants (from reference setup_inputs):
//   images: [B=8, H=256, W=256, C=256] float32  (NHWC, C contiguous)
//   boxes:  [B=8, N=100, 4] float32  (y1, x1, y2, x2 normalized)
//   out:    [B=8, CROP_H=7, CROP_W=7, N=100, C=256] float32
#define BB 8
#define HH 256
#define WW 256
#define CC 256
#define NN 100
#define CROP_H 7
#define CROP_W 7
#define EXTRAP 1.0f

// One 64-lane group per (b,i,j,n) position; each lane does 4 channels (float4).
// Block = 256 threads = 4 positions. Total positions = 8*7*7*100 = 39200.

__global__ __launch_bounds__(256) void roialign_kernel(
    const float* __restrict__ images,
    const float* __restrict__ boxes,
    float* __restrict__ out)
{
    const int tid  = threadIdx.x;
    const int sub  = tid >> 6;   // which of the 4 positions in this block
    const int lane = tid & 63;   // channel group: channels [4*lane, 4*lane+3]

    const int pos = blockIdx.x * 4 + sub;   // 0 .. 39199
    // pos = ((b*7 + i)*7 + j)*100 + n   — identical to the output's leading index
    int r = pos;
    const int n = r % NN; r /= NN;
    const int j = r % CROP_W; r /= CROP_W;
    const int i = r % CROP_H;
    const int b = r / CROP_H;

    // Load box (same values across the 64-lane group; scalar-cached)
    const float* bx = boxes + ((b * NN + n) << 2);
    const float y1 = bx[0];
    const float x1 = bx[1];
    const float y2 = bx[2];
    const float x2 = bx[3];

    // Mirror reference op order: in_y = y1*(H-1) + i * ((y2-y1)*(H-1)/(CROP_H-1))
    const float sy   = (y2 - y1) * 255.0f / 6.0f;
    const float sx   = (x2 - x1) * 255.0f / 6.0f;
    const float in_y = y1 * 255.0f + (float)i * sy;
    const float in_x = x1 * 255.0f + (float)j * sx;

    const bool valid = (in_y >= 0.0f) && (in_y <= 255.0f) &&
                       (in_x >= 0.0f) && (in_x <= 255.0f);

    // Output pointer: out[pos*256 + 4*lane] as float4
    float4* outp = reinterpret_cast<float4*>(out) + (size_t)pos * (CC / 4) + lane;

    if (!valid) {
        *outp = make_float4(EXTRAP, EXTRAP, EXTRAP, EXTRAP);
        return;
    }

    const float y0f = floorf(in_y);
    const float x0f = floorf(in_x);
    const float ly  = in_y - y0f;
    const float lx  = in_x - x0f;

    const int y0  = (int)fminf(fmaxf(y0f, 0.0f), 255.0f);
    const int y1i = (int)fminf(fmaxf(ceilf(in_y), 0.0f), 255.0f);
    const int x0  = (int)fminf(fmaxf(x0f, 0.0f), 255.0f);
    const int x1i = (int)fminf(fmaxf(ceilf(in_x), 0.0f), 255.0f);

    const float* img = images + (size_t)b * (HH * WW * CC);
    const float4* p00 = reinterpret_cast<const float4*>(img + ((size_t)(y0  * WW + x0 ) * CC)) + lane;
    const float4* p01 = reinterpret_cast<const float4*>(img + ((size_t)(y0  * WW + x1i) * CC)) + lane;
    const float4* p10 = reinterpret_cast<const float4*>(img + ((size_t)(y1i * WW + x0 ) * CC)) + lane;
    const float4* p11 = reinterpret_cast<const float4*>(img + ((size_t)(y1i * WW + x1i) * CC)) + lane;

    const float4 v00 = *p00;
    const float4 v01 = *p01;
    const float4 v10 = *p10;
    const float4 v11 = *p11;

    const float omx = 1.0f - lx;
    const float omy = 1.0f - ly;

    float4 res;
    {
        const float top_x = v00.x * omx + v01.x * lx;
        const float bot_x = v10.x * omx + v11.x * lx;
        res.x = top_x * omy + bot_x * ly;
        const float top_y = v00.y * omx + v01.y * lx;
        const float bot_y = v10.y * omx + v11.y * lx;
        res.y = top_y * omy + bot_y * ly;
        const float top_z = v00.z * omx + v01.z * lx;
        const float bot_z = v10.z * omx + v11.z * lx;
        res.z = top_z * omy + bot_z * ly;
        const float top_w = v00.w * omx + v01.w * lx;
        const float bot_w = v10.w * omx + v11.w * lx;
        res.w = top_w * omy + bot_w * ly;
    }

    *outp = res;
}

extern "C" void kernel_launch(void* const* d_in, const int* in_sizes, int n_in,
                              void* d_out, int out_size, void* d_ws, size_t ws_size,
                              hipStream_t stream) {
    const float* images = (const float*)d_in[0];
    const float* boxes  = (const float*)d_in[1];
    float* out = (float*)d_out;

    const int total_pos = BB * CROP_H * CROP_W * NN;   // 39200
    const int blocks = total_pos / 4;                  // 9800 (exact)
    roialign_kernel<<<blocks, 256, 0, stream>>>(images, boxes, out);
}

// Round 2
// 34.255 us; speedup vs baseline: 1.0046x; 1.0046x over previous
//
#include <hip/hip_runtime.h>

// Problem constants (from reference setup_inputs):
//   images: [B=8, H=256, W=256, C=256] float32  (NHWC, C contiguous)
//   boxes:  [B=8, N=100, 4] float32  (y1, x1, y2, x2 normalized)
//   out:    [B=8, CROP_H=7, CROP_W=7, N=100, C=256] float32
#define BB 8
#define HH 256
#define WW 256
#define CC 256
#define NN 100
#define CROP_H 7
#define CROP_W 7
#define EXTRAP 1.0f

typedef float f32x4 __attribute__((ext_vector_type(4)));

// One 64-lane group per (b,i,j,n) position; each lane does 4 channels (float4).
// Block = 256 threads = 4 positions. Total positions = 8*7*7*100 = 39200.
// Output stores are non-temporal: the 40 MB write stream is write-once and
// would otherwise evict the read-reuse working set from the 4 MB/XCD L2.

__global__ __launch_bounds__(256) void roialign_kernel(
    const float* __restrict__ images,
    const float* __restrict__ boxes,
    float* __restrict__ out)
{
    const int tid  = threadIdx.x;
    const int sub  = tid >> 6;   // which of the 4 positions in this block
    const int lane = tid & 63;   // channel group: channels [4*lane, 4*lane+3]

    const int pos = blockIdx.x * 4 + sub;   // 0 .. 39199
    // pos = ((b*7 + i)*7 + j)*100 + n   — identical to the output's leading index
    int r = pos;
    const int n = r % NN; r /= NN;
    const int j = r % CROP_W; r /= CROP_W;
    const int i = r % CROP_H;
    const int b = r / CROP_H;

    // Load box (same values across the 64-lane group; broadcast from cache)
    const float* bx = boxes + ((b * NN + n) << 2);
    const float y1 = bx[0];
    const float x1 = bx[1];
    const float y2 = bx[2];
    const float x2 = bx[3];

    // Mirror reference op order: in_y = y1*(H-1) + i * ((y2-y1)*(H-1)/(CROP_H-1))
    const float sy   = (y2 - y1) * 255.0f / 6.0f;
    const float sx   = (x2 - x1) * 255.0f / 6.0f;
    const float in_y = y1 * 255.0f + (float)i * sy;
    const float in_x = x1 * 255.0f + (float)j * sx;

    const bool valid = (in_y >= 0.0f) && (in_y <= 255.0f) &&
                       (in_x >= 0.0f) && (in_x <= 255.0f);

    f32x4* outp = reinterpret_cast<f32x4*>(out) + (size_t)pos * (CC / 4) + lane;

    if (!valid) {
        f32x4 e = {EXTRAP, EXTRAP, EXTRAP, EXTRAP};
        __builtin_nontemporal_store(e, outp);
        return;
    }

    const float y0f = floorf(in_y);
    const float x0f = floorf(in_x);
    const float ly  = in_y - y0f;
    const float lx  = in_x - x0f;

    const int y0  = (int)fminf(fmaxf(y0f, 0.0f), 255.0f);
    const int y1i = (int)fminf(fmaxf(ceilf(in_y), 0.0f), 255.0f);
    const int x0  = (int)fminf(fmaxf(x0f, 0.0f), 255.0f);
    const int x1i = (int)fminf(fmaxf(ceilf(in_x), 0.0f), 255.0f);

    const float* img = images + (size_t)b * (HH * WW * CC);
    const f32x4* p00 = reinterpret_cast<const f32x4*>(img + ((size_t)(y0  * WW + x0 ) * CC)) + lane;
    const f32x4* p01 = reinterpret_cast<const f32x4*>(img + ((size_t)(y0  * WW + x1i) * CC)) + lane;
    const f32x4* p10 = reinterpret_cast<const f32x4*>(img + ((size_t)(y1i * WW + x0 ) * CC)) + lane;
    const f32x4* p11 = reinterpret_cast<const f32x4*>(img + ((size_t)(y1i * WW + x1i) * CC)) + lane;

    const f32x4 v00 = *p00;
    const f32x4 v01 = *p01;
    const f32x4 v10 = *p10;
    const f32x4 v11 = *p11;

    const float omx = 1.0f - lx;
    const float omy = 1.0f - ly;

    const f32x4 top = v00 * omx + v01 * lx;
    const f32x4 bot = v10 * omx + v11 * lx;
    const f32x4 res = top * omy + bot * ly;

    __builtin_nontemporal_store(res, outp);
}

extern "C" void kernel_launch(void* const* d_in, const int* in_sizes, int n_in,
                              void* d_out, int out_size, void* d_ws, size_t ws_size,
                              hipStream_t stream) {
    const float* images = (const float*)d_in[0];
    const float* boxes  = (const float*)d_in[1];
    float* out = (float*)d_out;

    const int total_pos = BB * CROP_H * CROP_W * NN;   // 39200
    const int blocks = total_pos / 4;                  // 9800 (exact)
    roialign_kernel<<<blocks, 256, 0, stream>>>(images, boxes, out);
}